// Round 9
// baseline (377.697 us; speedup 1.0000x reference)
//
#include <hip/hip_runtime.h>
#include <cstdint>
#include <cstddef>

// ExpertMLP: out[e] = gelu(x[e] @ wfc[e]) @ wproj[e]
// E=32, CAP=4096, D=256, H=1024. fp32 in/out, bf16 MFMA internally.
// Round 9 — UNFUSED m201-cadence GEMMs. H (bf16) materialized in d_ws.
//   GEMM1: [4096,256]@[256,1024] per expert, GELU epilogue -> H bf16
//   GEMM2: [4096,1024]@[1024,256] per expert -> out fp32
// 256x256 tiles, BK=32, ring-4 A/B slabs (128KB LDS), 2 phases per K-tile,
// ONE counted vmcnt per K-tile (8/4/0 drain ladder), B-frags read once per
// tile into regs, stages only overwrite barrier-retired ring slots.

#define NE   32
#define CAPN 4096
#define DDIM 256
#define HDIM 1024

typedef __bf16 bf16x8 __attribute__((ext_vector_type(8)));
typedef __bf16 bf16x4 __attribute__((ext_vector_type(4)));
typedef __bf16 bf16x2 __attribute__((ext_vector_type(2)));
typedef float  f32x4  __attribute__((ext_vector_type(4)));

#define AS1 __attribute__((address_space(1)))
#define AS3 __attribute__((address_space(3)))

__device__ __forceinline__ void gld_lds16(const void* g, void* l) {
  __builtin_amdgcn_global_load_lds((const AS1 uint32_t*)g, (AS3 uint32_t*)l, 16, 0, 0);
}

__device__ __forceinline__ float gelu_f(float x) {
  float x2 = x * x;
  float u  = x * __builtin_fmaf(0.1029432f, x2, 2.3022078f);
  float t  = __builtin_amdgcn_exp2f(u);
  float r  = __builtin_amdgcn_rcpf(t + 1.0f);
  return __builtin_fmaf(-x, r, x);
}

#define WV(n)   asm volatile("s_waitcnt vmcnt(" #n ")" ::: "memory")
#define LGKM0() asm volatile("s_waitcnt lgkmcnt(0)" ::: "memory")
#define SB0()   __builtin_amdgcn_sched_barrier(0)
#define BAR()   do { __builtin_amdgcn_s_barrier(); SB0(); } while (0)

// ---------------- pre-pass: transpose + cast fp32 -> bf16 -------------------
__global__ __launch_bounds__(256) void tcast_kernel(const float* __restrict__ in,
                                                    __bf16* __restrict__ outp,
                                                    int R, int C) {
  __shared__ __bf16 tl[64][72];
  const int cb = C >> 6;
  const int nb = (R >> 6) * cb;
  const int b  = blockIdx.x;
  const int e  = b / nb;
  const int t  = b - e * nb;
  const int br = t / cb;
  const int bc = t - br * cb;
  const float* src = in + ((size_t)e * R + (size_t)br * 64) * C + (size_t)bc * 64;
#pragma unroll
  for (int i = 0; i < 16; ++i) {
    int idx = i * 256 + threadIdx.x;
    int r = idx >> 6, c = idx & 63;
    tl[c][r] = (__bf16)src[(size_t)r * C + c];
  }
  __syncthreads();
  __bf16* dst = outp + ((size_t)e * C + (size_t)bc * 64) * R + (size_t)br * 64;
#pragma unroll
  for (int i = 0; i < 8; ++i) {
    int idx = i * 512 + threadIdx.x * 2;
    int c = idx >> 6, r = idx & 63;
    bf16x2 p;
    p[0] = tl[c][r];
    p[1] = tl[c][r + 1];
    *(bf16x2*)(dst + (size_t)c * R + r) = p;
  }
}

// ---------------- x fp32 -> bf16 flat cast ---------------------------------
__global__ __launch_bounds__(256) void xcast_kernel(const float* __restrict__ in,
                                                    __bf16* __restrict__ outp,
                                                    long n8) {
  long i = (long)blockIdx.x * 256 + threadIdx.x;
  const long stride = (long)gridDim.x * 256;
  for (; i < n8; i += stride) {
    float4 a0 = ((const float4*)in)[2 * i];
    float4 a1 = ((const float4*)in)[2 * i + 1];
    bf16x8 v;
    v[0] = (__bf16)a0.x; v[1] = (__bf16)a0.y; v[2] = (__bf16)a0.z; v[3] = (__bf16)a0.w;
    v[4] = (__bf16)a1.x; v[5] = (__bf16)a1.y; v[6] = (__bf16)a1.z; v[7] = (__bf16)a1.w;
    ((bf16x8*)outp)[i] = v;
  }
}

// ---------------- m201-cadence 256x256 GEMM --------------------------------
// C[r][m] = sum_k A[r][k]*B[m][k]; A rows = output cols (h or d), B rows = m.
// 8 waves: wr=w&1 (r-half 128), wq=w>>1 (m-quarter 64). acc[8][4] f32x4.
// LDS: A-ring 4x16KB @0, B-ring 4x16KB @65536. Slab [256 rows][32 k] bf16,
// row 64B = 4 slots16B, phys slot = s ^ ((row>>1)&3).
// NT = # 256-col tiles in output-col dim; NRTOT = total rows of A per expert.
template <int NKT, int NT, int NRTOT, int RSA, int RSB, bool G1E>
__global__ __launch_bounds__(512, 1) void gemm_tile(
    const __bf16* __restrict__ Aroot, const __bf16* __restrict__ Broot,
    void* __restrict__ outp, int e0) {
  extern __shared__ char smem[];
  const int tid = threadIdx.x;
  const int l15 = tid & 15, l4 = (tid >> 4) & 3, w = tid >> 6;
  const int wr = w & 1, wq = w >> 1;

  const int epb = 16 * NT;
  const int bid = blockIdx.x;
  const int e_l = bid / epb;
  const int t   = bid - e_l * epb;
  const int mt  = t / NT, ct = t - mt * NT;
  const int m0  = mt << 8, r0 = ct << 8;
  const int e_g = e0 + e_l;

  const __bf16* Ab = Aroot + ((size_t)e_g * NRTOT + r0) * RSA;
  const __bf16* Bb = Broot + ((size_t)e_l * CAPN + m0) * RSB;

  // staging lane geometry (LDS dest linear; swizzle in global source addr)
  const int sr  = tid >> 2;                       // row 0..127 (i adds 128)
  const int ssl = (tid & 3) ^ ((sr >> 1) & 3);    // same for i=0,1 (128 even)
  char* dstA = smem + tid * 16;
  char* dstB = smem + 65536 + tid * 16;

#define STAGE_A(T_) do {                                                       \
    const __bf16* s_ = Ab + (size_t)sr * RSA + (T_) * 32 + ssl * 8;            \
    gld_lds16(s_,              dstA + ((T_) & 3) * 16384);                     \
    gld_lds16(s_ + 128 * RSA,  dstA + ((T_) & 3) * 16384 + 8192);              \
  } while (0)

#define STAGE_B(T_) do {                                                       \
    const __bf16* s_ = Bb + (size_t)sr * RSB + (T_) * 32 + ssl * 8;            \
    gld_lds16(s_,              dstB + ((T_) & 3) * 16384);                     \
    gld_lds16(s_ + 128 * RSB,  dstB + ((T_) & 3) * 16384 + 8192);              \
  } while (0)

  // fragment read offsets
  const int physk = (l4 ^ ((l15 >> 1) & 3)) * 16;
  const int aoff  = (wr * 128 + l15) * 64 + physk;          // + rf*1024
  const int boff  = 65536 + (wq * 64 + l15) * 64 + physk;   // + fm*1024

  f32x4 zero = 0.0f;
  f32x4 acc[8][4];
#pragma unroll
  for (int a = 0; a < 8; ++a)
#pragma unroll
    for (int b = 0; b < 4; ++b) acc[a][b] = zero;

  // prologue: tiles 0,1,2 in flight (12 loads); oldest 4 = tile 0
  STAGE_A(0); STAGE_B(0);
  STAGE_A(1); STAGE_B(1);
  STAGE_A(2); STAGE_B(2);
  WV(8); BAR();

  for (int kt = 0; kt < NKT; ++kt) {
    const int buf = (kt & 3) * 16384;
    // ---- phase q0: bx (whole tile) + af quadrants 0-3 ----
    bf16x8 bx[4], af[4];
#pragma unroll
    for (int fm = 0; fm < 4; ++fm)
      bx[fm] = *(const bf16x8*)(smem + buf + boff + fm * 1024);
#pragma unroll
    for (int rf = 0; rf < 4; ++rf)
      af[rf] = *(const bf16x8*)(smem + buf + aoff + rf * 1024);
    if (kt + 3 < NKT) STAGE_A(kt + 3);
    BAR(); LGKM0(); SB0();
    __builtin_amdgcn_s_setprio(1);
#pragma unroll
    for (int rf = 0; rf < 4; ++rf)
#pragma unroll
      for (int fm = 0; fm < 4; ++fm)
        acc[rf][fm] = __builtin_amdgcn_mfma_f32_16x16x32_bf16(af[rf], bx[fm], acc[rf][fm], 0, 0, 0);
    __builtin_amdgcn_s_setprio(0);
    BAR();

    // ---- phase q1: af quadrants 4-7; counted vmcnt once per tile ----
#pragma unroll
    for (int rf = 0; rf < 4; ++rf)
      af[rf] = *(const bf16x8*)(smem + buf + aoff + (4 + rf) * 1024);
    if (kt + 3 < NKT) STAGE_B(kt + 3);
    if (kt < NKT - 3)       { WV(8); }
    else if (kt == NKT - 3) { WV(4); }
    else if (kt == NKT - 2) { WV(0); }
    BAR(); LGKM0(); SB0();
    __builtin_amdgcn_s_setprio(1);
#pragma unroll
    for (int rf = 0; rf < 4; ++rf)
#pragma unroll
      for (int fm = 0; fm < 4; ++fm)
        acc[4 + rf][fm] = __builtin_amdgcn_mfma_f32_16x16x32_bf16(af[rf], bx[fm], acc[4 + rf][fm], 0, 0, 0);
    __builtin_amdgcn_s_setprio(0);
    BAR();
  }

  // ---- epilogue ----
  if constexpr (G1E) {
    __bf16* Hp = (__bf16*)outp;  // [e_l][CAPN][HDIM], bf16, GELU applied
#pragma unroll
    for (int rf = 0; rf < 8; ++rf) {
#pragma unroll
      for (int fm = 0; fm < 4; ++fm) {
        int hg = r0 + wr * 128 + rf * 16 + l4 * 4;
        int mg = m0 + wq * 64 + fm * 16 + l15;
        bf16x4 hv;
#pragma unroll
        for (int j = 0; j < 4; ++j) hv[j] = (__bf16)gelu_f(acc[rf][fm][j]);
        *(bf16x4*)(Hp + ((size_t)e_l * CAPN + mg) * HDIM + hg) = hv;
      }
    }
  } else {
    float* Op = (float*)outp;    // [e_g][CAPN][DDIM] fp32
#pragma unroll
    for (int rf = 0; rf < 8; ++rf) {
#pragma unroll
      for (int fm = 0; fm < 4; ++fm) {
        int dg = r0 + wr * 128 + rf * 16 + l4 * 4;
        int mg = m0 + wq * 64 + fm * 16 + l15;
        *(f32x4*)(Op + ((size_t)e_g * CAPN + mg) * DDIM + dg) = acc[rf][fm];
      }
    }
  }
#undef STAGE_A
#undef STAGE_B
}

extern "C" void kernel_launch(void* const* d_in, const int* in_sizes, int n_in,
                              void* d_out, int out_size, void* d_ws, size_t ws_size,
                              hipStream_t stream) {
  (void)in_sizes; (void)n_in; (void)out_size;
  const float* x     = (const float*)d_in[0];
  const float* wfc   = (const float*)d_in[1];   // [E][D][H]
  const float* wproj = (const float*)d_in[2];   // [E][H][D]
  float* out = (float*)d_out;

  // ws layout: wfcT 16.78M | wprojT 16.78M | Xb ne*2M | H ne*8M
  const size_t WSZ = (size_t)NE * DDIM * HDIM * sizeof(__bf16);  // 16.78 MB
  int ne = NE;  // experts per group; shrink until scratch fits
  while (ne > 1 && 2 * WSZ + (size_t)ne * 10485760ull > ws_size) ne >>= 1;

  __bf16* wfcT   = (__bf16*)d_ws;
  __bf16* wprojT = (__bf16*)((char*)d_ws + WSZ);
  __bf16* Xb     = (__bf16*)((char*)d_ws + 2 * WSZ);
  __bf16* Hb     = (__bf16*)((char*)d_ws + 2 * WSZ + (size_t)ne * CAPN * DDIM * sizeof(__bf16));

  hipFuncSetAttribute((const void*)&gemm_tile<8, 4, 1024, 256, 256, true>,
                      hipFuncAttributeMaxDynamicSharedMemorySize, 131072);
  hipFuncSetAttribute((const void*)&gemm_tile<32, 1, 256, 1024, 1024, false>,
                      hipFuncAttributeMaxDynamicSharedMemorySize, 131072);

  tcast_kernel<<<dim3(NE * 64), dim3(256), 0, stream>>>(wfc, wfcT, DDIM, HDIM);
  tcast_kernel<<<dim3(NE * 64), dim3(256), 0, stream>>>(wproj, wprojT, HDIM, DDIM);

  const int ngroups = NE / ne;
  for (int g = 0; g < ngroups; ++g) {
    const int e0 = g * ne;
    xcast_kernel<<<dim3(1024), dim3(256), 0, stream>>>(
        x + (size_t)e0 * CAPN * DDIM, Xb, (long)ne * CAPN * DDIM / 8);
    gemm_tile<8, 4, 1024, 256, 256, true>
        <<<dim3(ne * 64), dim3(512), 131072, stream>>>(wfcT, Xb, Hb, e0);
    gemm_tile<32, 1, 256, 1024, 1024, false>
        <<<dim3(ne * 16), dim3(512), 131072, stream>>>(wprojT, Hb, out, e0);
  }
}

// Round 10
// 321.587 us; speedup vs baseline: 1.1745x; 1.1745x over previous
//
#include <hip/hip_runtime.h>
#include <cstdint>
#include <cstddef>

// ExpertMLP: out[e] = gelu(x[e] @ wfc[e]) @ wproj[e]
// E=32, CAP=4096, D=256, H=1024. fp32 in/out, bf16 MFMA internally.
// Round 10 — unfused m201-cadence GEMMs with COALESCED epilogues:
//   GEMM1: LDS-transpose epilogue (128KB tile, retired rings reused) -> H bf16
//   GEMM2: swapped operand roles (A=H rows m, B=W rows d) -> D lane axis = d
//          -> f32 stores are full-cache-line coalesced, no LDS needed
// Expert groups ne=16: group H (134MB) + X (34MB) stay L3-resident; GEMM2
// grid = 256 blocks = 1/CU. Ring-4 slabs, one counted vmcnt per K-tile.

#define NE   32
#define CAPN 4096
#define DDIM 256
#define HDIM 1024

typedef __bf16 bf16x8 __attribute__((ext_vector_type(8)));
typedef __bf16 bf16x4 __attribute__((ext_vector_type(4)));
typedef __bf16 bf16x2 __attribute__((ext_vector_type(2)));
typedef float  f32x4  __attribute__((ext_vector_type(4)));

#define AS1 __attribute__((address_space(1)))
#define AS3 __attribute__((address_space(3)))

__device__ __forceinline__ void gld_lds16(const void* g, void* l) {
  __builtin_amdgcn_global_load_lds((const AS1 uint32_t*)g, (AS3 uint32_t*)l, 16, 0, 0);
}

__device__ __forceinline__ float gelu_f(float x) {
  float x2 = x * x;
  float u  = x * __builtin_fmaf(0.1029432f, x2, 2.3022078f);
  float t  = __builtin_amdgcn_exp2f(u);
  float r  = __builtin_amdgcn_rcpf(t + 1.0f);
  return __builtin_fmaf(-x, r, x);
}

#define WV(n)   asm volatile("s_waitcnt vmcnt(" #n ")" ::: "memory")
#define LGKM0() asm volatile("s_waitcnt lgkmcnt(0)" ::: "memory")
#define SB0()   __builtin_amdgcn_sched_barrier(0)
#define BAR()   do { __builtin_amdgcn_s_barrier(); SB0(); } while (0)

// ---------------- pre-pass: transpose + cast fp32 -> bf16 -------------------
__global__ __launch_bounds__(256) void tcast_kernel(const float* __restrict__ in,
                                                    __bf16* __restrict__ outp,
                                                    int R, int C) {
  __shared__ __bf16 tl[64][72];
  const int cb = C >> 6;
  const int nb = (R >> 6) * cb;
  const int b  = blockIdx.x;
  const int e  = b / nb;
  const int t  = b - e * nb;
  const int br = t / cb;
  const int bc = t - br * cb;
  const float* src = in + ((size_t)e * R + (size_t)br * 64) * C + (size_t)bc * 64;
#pragma unroll
  for (int i = 0; i < 16; ++i) {
    int idx = i * 256 + threadIdx.x;
    int r = idx >> 6, c = idx & 63;
    tl[c][r] = (__bf16)src[(size_t)r * C + c];
  }
  __syncthreads();
  __bf16* dst = outp + ((size_t)e * C + (size_t)bc * 64) * R + (size_t)br * 64;
#pragma unroll
  for (int i = 0; i < 8; ++i) {
    int idx = i * 512 + threadIdx.x * 2;
    int c = idx >> 6, r = idx & 63;
    bf16x2 p;
    p[0] = tl[c][r];
    p[1] = tl[c][r + 1];
    *(bf16x2*)(dst + (size_t)c * R + r) = p;
  }
}

// ---------------- x fp32 -> bf16 flat cast ---------------------------------
__global__ __launch_bounds__(256) void xcast_kernel(const float* __restrict__ in,
                                                    __bf16* __restrict__ outp,
                                                    long n8) {
  long i = (long)blockIdx.x * 256 + threadIdx.x;
  const long stride = (long)gridDim.x * 256;
  for (; i < n8; i += stride) {
    float4 a0 = ((const float4*)in)[2 * i];
    float4 a1 = ((const float4*)in)[2 * i + 1];
    bf16x8 v;
    v[0] = (__bf16)a0.x; v[1] = (__bf16)a0.y; v[2] = (__bf16)a0.z; v[3] = (__bf16)a0.w;
    v[4] = (__bf16)a1.x; v[5] = (__bf16)a1.y; v[6] = (__bf16)a1.z; v[7] = (__bf16)a1.w;
    ((bf16x8*)outp)[i] = v;
  }
}

// Shared slab geometry: slab [256 rows][32 k] bf16, 64B rows = 4 slots16B,
// phys slot = s ^ ((row>>1)&3). A-ring 4x16KB @0, B-ring 4x16KB @65536.

// ============ GEMM1: H[m][h] = gelu(sum_d Wfc^T[h][d] * X[m][d]) ============
// A = wfcT rows h (256-tile), B = Xb rows m (256-tile), NKT=8.
// Epilogue: LDS-transpose -> coalesced 16B H writes.
__global__ __launch_bounds__(512, 1) void gemm1_fc(
    const __bf16* __restrict__ wfcT, const __bf16* __restrict__ Xb,
    __bf16* __restrict__ Hb, int e0) {
  extern __shared__ char smem[];
  const int tid = threadIdx.x;
  const int l15 = tid & 15, l4 = (tid >> 4) & 3, w = tid >> 6;
  const int wr = w & 1, wq = w >> 1;

  const int bid = blockIdx.x;
  const int e_l = bid >> 6;
  const int t   = bid & 63;
  const int mt  = t >> 2, ct = t & 3;
  const int m0  = mt << 8, r0 = ct << 8;

  const __bf16* Ab = wfcT + ((size_t)((e0 + e_l) * HDIM + r0)) * DDIM;
  const __bf16* Bb = Xb + ((size_t)(e_l * CAPN + m0)) * DDIM;

  const int sr  = tid >> 2;
  const int ssl = (tid & 3) ^ ((sr >> 1) & 3);
  char* dstA = smem + tid * 16;
  char* dstB = smem + 65536 + tid * 16;

#define STAGE_A1(T_) do {                                                      \
    const __bf16* s_ = Ab + (size_t)sr * DDIM + (T_) * 32 + ssl * 8;           \
    gld_lds16(s_,             dstA + ((T_) & 3) * 16384);                      \
    gld_lds16(s_ + 128 * DDIM, dstA + ((T_) & 3) * 16384 + 8192);              \
  } while (0)
#define STAGE_B1(T_) do {                                                      \
    const __bf16* s_ = Bb + (size_t)sr * DDIM + (T_) * 32 + ssl * 8;           \
    gld_lds16(s_,             dstB + ((T_) & 3) * 16384);                      \
    gld_lds16(s_ + 128 * DDIM, dstB + ((T_) & 3) * 16384 + 8192);              \
  } while (0)

  const int physk = (l4 ^ ((l15 >> 1) & 3)) * 16;
  const int aoff  = (wr * 128 + l15) * 64 + physk;
  const int boff  = 65536 + (wq * 64 + l15) * 64 + physk;

  f32x4 zero = 0.0f;
  f32x4 acc[8][4];
#pragma unroll
  for (int a = 0; a < 8; ++a)
#pragma unroll
    for (int b = 0; b < 4; ++b) acc[a][b] = zero;

  STAGE_A1(0); STAGE_B1(0);
  STAGE_A1(1); STAGE_B1(1);
  STAGE_A1(2); STAGE_B1(2);
  WV(8); BAR();

#pragma unroll 2
  for (int kt = 0; kt < 8; ++kt) {
    const int buf = (kt & 3) * 16384;
    bf16x8 bx[4], af[4];
#pragma unroll
    for (int fm = 0; fm < 4; ++fm)
      bx[fm] = *(const bf16x8*)(smem + buf + boff + fm * 1024);
#pragma unroll
    for (int rf = 0; rf < 4; ++rf)
      af[rf] = *(const bf16x8*)(smem + buf + aoff + rf * 1024);
    if (kt + 3 < 8) STAGE_A1(kt + 3);
    BAR(); LGKM0(); SB0();
    __builtin_amdgcn_s_setprio(1);
#pragma unroll
    for (int rf = 0; rf < 4; ++rf)
#pragma unroll
      for (int fm = 0; fm < 4; ++fm)
        acc[rf][fm] = __builtin_amdgcn_mfma_f32_16x16x32_bf16(af[rf], bx[fm], acc[rf][fm], 0, 0, 0);
    __builtin_amdgcn_s_setprio(0);
    BAR();

#pragma unroll
    for (int rf = 0; rf < 4; ++rf)
      af[rf] = *(const bf16x8*)(smem + buf + aoff + (4 + rf) * 1024);
    if (kt + 3 < 8) STAGE_B1(kt + 3);
    if (kt < 5)       { WV(8); }
    else if (kt == 5) { WV(4); }
    else if (kt == 6) { WV(0); }
    BAR(); LGKM0(); SB0();
    __builtin_amdgcn_s_setprio(1);
#pragma unroll
    for (int rf = 0; rf < 4; ++rf)
#pragma unroll
      for (int fm = 0; fm < 4; ++fm)
        acc[4 + rf][fm] = __builtin_amdgcn_mfma_f32_16x16x32_bf16(af[rf], bx[fm], acc[4 + rf][fm], 0, 0, 0);
    __builtin_amdgcn_s_setprio(0);
    BAR();
  }

  // ---- epilogue: GELU -> LDS [256 m][256 h] swizzled -> coalesced writes ----
  // (rings fully retired: last stage drained by kt==6 WV(0))
#pragma unroll
  for (int rf = 0; rf < 8; ++rf) {
#pragma unroll
    for (int fm = 0; fm < 4; ++fm) {
      const int hl = wr * 128 + rf * 16 + l4 * 4;
      const int ml = wq * 64 + fm * 16 + l15;
      bf16x4 hv;
#pragma unroll
      for (int j = 0; j < 4; ++j) hv[j] = (__bf16)gelu_f(acc[rf][fm][j]);
      const int s    = hl >> 3;
      const int half = (hl >> 2) & 1;
      const int phys = (s & 24) | ((s & 7) ^ (ml & 7));
      *(bf16x4*)(smem + ml * 512 + phys * 16 + half * 8) = hv;
    }
  }
  LGKM0(); BAR();
  __bf16* Hp = Hb + ((size_t)(e_l * CAPN + m0)) * HDIM + r0;
#pragma unroll
  for (int i = 0; i < 16; ++i) {
    const int sid = i * 512 + tid;
    const int ml  = sid >> 5;
    const int s   = sid & 31;
    const int phys = (s & 24) | ((s & 7) ^ (ml & 7));
    bf16x8 v = *(const bf16x8*)(smem + ml * 512 + phys * 16);
    *(bf16x8*)(Hp + (size_t)ml * HDIM + s * 8) = v;
  }
#undef STAGE_A1
#undef STAGE_B1
}

// ============ GEMM2: out[m][d] = sum_h H[m][h] * Wproj^T[d][h] ==============
// A = Hb rows m (256-tile) -> D reg axis = m; B = wprojT rows d (256) ->
// D lane axis = d -> coalesced f32 stores (full 64B lines). NKT=32.
__global__ __launch_bounds__(512, 1) void gemm2_pj(
    const __bf16* __restrict__ Hb, const __bf16* __restrict__ wprojT,
    float* __restrict__ out, int e0) {
  extern __shared__ char smem[];
  const int tid = threadIdx.x;
  const int l15 = tid & 15, l4 = (tid >> 4) & 3, w = tid >> 6;
  const int wr = w & 1, wq = w >> 1;

  const int bid = blockIdx.x;
  const int e_l = bid >> 4;
  const int m0  = (bid & 15) << 8;

  const __bf16* Ab = Hb + ((size_t)(e_l * CAPN + m0)) * HDIM;
  const __bf16* Bb = wprojT + (size_t)(e0 + e_l) * DDIM * HDIM;

  const int sr  = tid >> 2;
  const int ssl = (tid & 3) ^ ((sr >> 1) & 3);
  char* dstA = smem + tid * 16;
  char* dstB = smem + 65536 + tid * 16;

#define STAGE_A2(T_) do {                                                      \
    const __bf16* s_ = Ab + (size_t)sr * HDIM + (T_) * 32 + ssl * 8;           \
    gld_lds16(s_,              dstA + ((T_) & 3) * 16384);                     \
    gld_lds16(s_ + 128 * HDIM, dstA + ((T_) & 3) * 16384 + 8192);              \
  } while (0)
#define STAGE_B2(T_) do {                                                      \
    const __bf16* s_ = Bb + (size_t)sr * HDIM + (T_) * 32 + ssl * 8;           \
    gld_lds16(s_,              dstB + ((T_) & 3) * 16384);                     \
    gld_lds16(s_ + 128 * HDIM, dstB + ((T_) & 3) * 16384 + 8192);              \
  } while (0)

  const int physk = (l4 ^ ((l15 >> 1) & 3)) * 16;
  const int aoff  = (wr * 128 + l15) * 64 + physk;          // rows m
  const int boff  = 65536 + (wq * 64 + l15) * 64 + physk;   // rows d

  f32x4 zero = 0.0f;
  f32x4 acc[8][4];
#pragma unroll
  for (int a = 0; a < 8; ++a)
#pragma unroll
    for (int b = 0; b < 4; ++b) acc[a][b] = zero;

  STAGE_A2(0); STAGE_B2(0);
  STAGE_A2(1); STAGE_B2(1);
  STAGE_A2(2); STAGE_B2(2);
  WV(8); BAR();

#pragma unroll 2
  for (int kt = 0; kt < 32; ++kt) {
    const int buf = (kt & 3) * 16384;
    bf16x8 bx[4], af[4];
#pragma unroll
    for (int fm = 0; fm < 4; ++fm)
      bx[fm] = *(const bf16x8*)(smem + buf + boff + fm * 1024);
#pragma unroll
    for (int rf = 0; rf < 4; ++rf)
      af[rf] = *(const bf16x8*)(smem + buf + aoff + rf * 1024);
    if (kt + 3 < 32) STAGE_A2(kt + 3);
    BAR(); LGKM0(); SB0();
    __builtin_amdgcn_s_setprio(1);
#pragma unroll
    for (int rf = 0; rf < 4; ++rf)
#pragma unroll
      for (int fm = 0; fm < 4; ++fm)
        acc[rf][fm] = __builtin_amdgcn_mfma_f32_16x16x32_bf16(af[rf], bx[fm], acc[rf][fm], 0, 0, 0);
    __builtin_amdgcn_s_setprio(0);
    BAR();

#pragma unroll
    for (int rf = 0; rf < 4; ++rf)
      af[rf] = *(const bf16x8*)(smem + buf + aoff + (4 + rf) * 1024);
    if (kt + 3 < 32) STAGE_B2(kt + 3);
    if (kt < 29)       { WV(8); }
    else if (kt == 29) { WV(4); }
    else if (kt == 30) { WV(0); }
    BAR(); LGKM0(); SB0();
    __builtin_amdgcn_s_setprio(1);
#pragma unroll
    for (int rf = 0; rf < 4; ++rf)
#pragma unroll
      for (int fm = 0; fm < 4; ++fm)
        acc[4 + rf][fm] = __builtin_amdgcn_mfma_f32_16x16x32_bf16(af[rf], bx[fm], acc[4 + rf][fm], 0, 0, 0);
    __builtin_amdgcn_s_setprio(0);
    BAR();
  }

  // ---- epilogue: D reg axis = m, lane axis = d -> line-coalesced f32 ----
  float* Op = out + ((size_t)((e0 + e_l) * CAPN + m0)) * DDIM;
#pragma unroll
  for (int rf = 0; rf < 8; ++rf) {
#pragma unroll
    for (int fm = 0; fm < 4; ++fm) {
      const int d = wq * 64 + fm * 16 + l15;
#pragma unroll
      for (int j = 0; j < 4; ++j) {
        const int m = wr * 128 + rf * 16 + l4 * 4 + j;
        Op[(size_t)m * DDIM + d] = acc[rf][fm][j];
      }
    }
  }
#undef STAGE_A2
#undef STAGE_B2
}

extern "C" void kernel_launch(void* const* d_in, const int* in_sizes, int n_in,
                              void* d_out, int out_size, void* d_ws, size_t ws_size,
                              hipStream_t stream) {
  (void)in_sizes; (void)n_in; (void)out_size;
  const float* x     = (const float*)d_in[0];
  const float* wfc   = (const float*)d_in[1];   // [E][D][H]
  const float* wproj = (const float*)d_in[2];   // [E][H][D]
  float* out = (float*)d_out;

  const size_t WSZ = (size_t)NE * DDIM * HDIM * sizeof(__bf16);  // 16.78 MB
  const size_t PER = (size_t)CAPN * DDIM * 2 + (size_t)CAPN * HDIM * 2;  // 10.5MB/e
  int ne = 16;
  while (ne > 1 && 2 * WSZ + (size_t)ne * PER > ws_size) ne >>= 1;

  __bf16* wfcT   = (__bf16*)d_ws;
  __bf16* wprojT = (__bf16*)((char*)d_ws + WSZ);
  __bf16* Xb     = (__bf16*)((char*)d_ws + 2 * WSZ);
  __bf16* Hb     = (__bf16*)((char*)d_ws + 2 * WSZ + (size_t)ne * CAPN * DDIM * 2);

  hipFuncSetAttribute((const void*)gemm1_fc,
                      hipFuncAttributeMaxDynamicSharedMemorySize, 131072);
  hipFuncSetAttribute((const void*)gemm2_pj,
                      hipFuncAttributeMaxDynamicSharedMemorySize, 131072);

  tcast_kernel<<<dim3(NE * 64), dim3(256), 0, stream>>>(wfc, wfcT, DDIM, HDIM);
  tcast_kernel<<<dim3(NE * 64), dim3(256), 0, stream>>>(wproj, wprojT, HDIM, DDIM);

  const int ngroups = NE / ne;
  for (int g = 0; g < ngroups; ++g) {
    const int e0 = g * ne;
    xcast_kernel<<<dim3(1024), dim3(256), 0, stream>>>(
        x + (size_t)e0 * CAPN * DDIM, Xb, (long)ne * CAPN * DDIM / 8);
    gemm1_fc<<<dim3(ne * 64), dim3(512), 131072, stream>>>(wfcT, Xb, Hb, e0);
    gemm2_pj<<<dim3(ne * 16), dim3(512), 131072, stream>>>(Hb, wprojT, out, e0);
  }
}